// Round 1
// 447.743 us; speedup vs baseline: 1.2130x; 1.2130x over previous
//
#include <hip/hip_runtime.h>
#include <cstdint>
#include <cstddef>

#define SEQ 2048
#define DMODEL 1024
#define NHEADS 16
#define HDIM 64

typedef __attribute__((ext_vector_type(8))) short short8;
typedef __attribute__((ext_vector_type(4))) float floatx4;

__device__ __forceinline__ short f2bf(float f) {
  union { float f; uint32_t u; } x; x.f = f;
  uint32_t r = (x.u + 0x7FFFu + ((x.u >> 16) & 1u)) >> 16;
  return (short)(uint16_t)r;
}

__device__ __forceinline__ void gl_lds16(const short* g, short* l) {
  __builtin_amdgcn_global_load_lds((const __attribute__((address_space(1))) void*)g,
                                   (__attribute__((address_space(3))) void*)l, 16, 0, 0);
}

// ---------------- cast fp32 -> bf16 ----------------
__global__ __launch_bounds__(256) void cast_bf16_kernel(const float* __restrict__ src,
                                                        short* __restrict__ dst, int n) {
  int i = blockIdx.x * 256 + threadIdx.x;
  if (i < n) dst[i] = f2bf(src[i]);
}

// ---------------- transpose 1024x1024 fp32 -> bf16 (W[d][n] -> Wt[n][d]) ----------------
__global__ __launch_bounds__(256) void transpose_cast_kernel(const float* __restrict__ src,
                                                             short* __restrict__ dst) {
  __shared__ float tile[32][33];
  int tx = threadIdx.x, ty = threadIdx.y;
  int x = blockIdx.x * 32 + tx;
  int y0 = blockIdx.y * 32;
#pragma unroll
  for (int j = 0; j < 32; j += 8)
    tile[ty + j][tx] = src[(size_t)(y0 + ty + j) * DMODEL + x];
  __syncthreads();
  int xo = blockIdx.y * 32 + tx;
  int yo0 = blockIdx.x * 32;
#pragma unroll
  for (int j = 0; j < 32; j += 8)
    dst[(size_t)(yo0 + ty + j) * DMODEL + xo] = f2bf(tile[tx][ty + j]);
}

// ---------------- QKV GEMM: m97-structure 128x128 tile, BK=32, global_load_lds ----------------
// C[2048][3072] = Xb[2048][1024] * Wt^T ; q/k head-major, vT transposed via swapped-operand MFMA.
__global__ __launch_bounds__(256) void qkv_gemm_kernel(const short* __restrict__ Xb,
                                                       const short* __restrict__ Wt,
                                                       short* __restrict__ q,
                                                       short* __restrict__ k,
                                                       short* __restrict__ vT) {
  __shared__ short Abuf[128 * 32];
  __shared__ short Bbuf[128 * 32];
  int tid = threadIdx.x;
  int wave = tid >> 6, lane = tid & 63;
  int lr = lane & 15, quad = lane >> 4;
  int m0 = blockIdx.y * 128;
  int n0 = blockIdx.x * 128;
  int wr = wave >> 1, wc = wave & 1;

  // staging: thread t loads 16B from row (t>>2), col (t&3)*8; two row-blocks of 64
  const short* Ag = Xb + (size_t)(m0 + (tid >> 2)) * DMODEL + (tid & 3) * 8;
  const short* Bg = Wt + (size_t)(n0 + (tid >> 2)) * DMODEL + (tid & 3) * 8;
  short* Al = Abuf + wave * 512;  // wave-uniform LDS base (16 rows * 32)
  short* Bl = Bbuf + wave * 512;

  floatx4 acc[4][4] = {};
  bool isV = (n0 >= 2 * DMODEL);

  for (int kb = 0; kb < DMODEL; kb += 32) {
    __syncthreads();  // protect LDS vs previous iteration's reads
    gl_lds16(Ag + kb, Al);
    gl_lds16(Ag + kb + 64 * DMODEL, Al + 2048);
    gl_lds16(Bg + kb, Bl);
    gl_lds16(Bg + kb + 64 * DMODEL, Bl + 2048);
    __syncthreads();  // vmcnt(0) drain -> tiles ready

    short8 a[4], b[4];
#pragma unroll
    for (int i = 0; i < 4; ++i) {
      a[i] = *(const short8*)(Abuf + (wr * 64 + i * 16 + lr) * 32 + quad * 8);
      b[i] = *(const short8*)(Bbuf + (wc * 64 + i * 16 + lr) * 32 + quad * 8);
    }
    if (isV) {
      // swapped operands: acc holds C^T fragment (rows=n, cols=m) for coalesced vT store
#pragma unroll
      for (int mi = 0; mi < 4; ++mi)
#pragma unroll
        for (int ni = 0; ni < 4; ++ni)
          acc[mi][ni] = __builtin_amdgcn_mfma_f32_16x16x32_bf16(b[ni], a[mi], acc[mi][ni], 0, 0, 0);
    } else {
#pragma unroll
      for (int mi = 0; mi < 4; ++mi)
#pragma unroll
        for (int ni = 0; ni < 4; ++ni)
          acc[mi][ni] = __builtin_amdgcn_mfma_f32_16x16x32_bf16(a[mi], b[ni], acc[mi][ni], 0, 0, 0);
    }
  }

  if (!isV) {
    short* out = (n0 < DMODEL) ? q : k;
    int nbase = n0 & (DMODEL - 1);
#pragma unroll
    for (int mi = 0; mi < 4; ++mi)
#pragma unroll
      for (int ni = 0; ni < 4; ++ni) {
        int n = nbase + wc * 64 + ni * 16 + lr;
        int hh = n >> 6, d = n & 63;
        size_t base = ((size_t)hh * SEQ + m0 + wr * 64 + mi * 16 + quad * 4) * HDIM + d;
#pragma unroll
        for (int r = 0; r < 4; ++r) out[base + (size_t)r * HDIM] = f2bf(acc[mi][ni][r]);
      }
  } else {
    // acc is transposed: reg-row = n-local, lane&15 = m-local (s)
    int nbase = n0 - 2 * DMODEL;  // == h*64+d flat index into vT rows
#pragma unroll
    for (int mi = 0; mi < 4; ++mi) {
      int sidx = m0 + wr * 64 + mi * 16 + lr;
#pragma unroll
      for (int ni = 0; ni < 4; ++ni) {
        int n = nbase + wc * 64 + ni * 16 + quad * 4;
#pragma unroll
        for (int r = 0; r < 4; ++r) vT[(size_t)(n + r) * SEQ + sidx] = f2bf(acc[mi][ni][r]);
      }
    }
  }
}

// ---------------- Fused attention: scores + softmax + coalesced probs + PV ----------------
// Block = 1 head x 16 Q rows. 4 waves each own 512 score cols in registers.
// Wave-private fp32 LDS chunk [16][128] serves BOTH the coalesced probs store
// (dwordx4, 512B row segments, non-temporal) AND the PV bf16 A-fragment reads.
#define PSTRF 132  // fp32 row stride, padded

__global__ __launch_bounds__(256) void attn_fused_kernel(const short* __restrict__ q,
                                                         const short* __restrict__ k,
                                                         const short* __restrict__ vT,
                                                         float* __restrict__ probs,
                                                         float* __restrict__ ctx) {
  __shared__ float pf[4][16 * PSTRF];    // wave-private fp32 P chunks
  __shared__ float partial[4][16][64];   // per-wave PV partials
  __shared__ float wred[4][16];          // cross-wave softmax reduce

  int h = blockIdx.y;
  int m0 = blockIdx.x * 16;
  int wave = threadIdx.x >> 6, lane = threadIdx.x & 63;
  int lr = lane & 15, quad = lane >> 4;
  int nb = wave * 512;

  // Q fragment: A[m=lr][k=quad*8+j], two 32-k steps
  const short* Q = q + ((size_t)h * SEQ + m0 + lr) * HDIM + quad * 8;
  short8 qa0 = *(const short8*)(Q);
  short8 qa1 = *(const short8*)(Q + 32);

  const short* K = k + (size_t)h * SEQ * HDIM + quad * 8;

  // ---- scores: 16 x 512 per wave, held in 32 floatx4 accumulators ----
  floatx4 s[32];
#pragma unroll
  for (int f = 0; f < 32; ++f) {
    const short* Kr = K + (size_t)(nb + f * 16 + lr) * HDIM;
    short8 b0 = *(const short8*)(Kr);
    short8 b1 = *(const short8*)(Kr + 32);
    floatx4 t = {};
    t = __builtin_amdgcn_mfma_f32_16x16x32_bf16(qa0, b0, t, 0, 0, 0);
    s[f] = __builtin_amdgcn_mfma_f32_16x16x32_bf16(qa1, b1, t, 0, 0, 0);
  }

  // ---- row max (scale by 1/8 first) ----
  float mrow[4] = {-3.4e38f, -3.4e38f, -3.4e38f, -3.4e38f};
#pragma unroll
  for (int f = 0; f < 32; ++f)
#pragma unroll
    for (int r = 0; r < 4; ++r) {
      s[f][r] *= 0.125f;
      mrow[r] = fmaxf(mrow[r], s[f][r]);
    }
#pragma unroll
  for (int off = 8; off >= 1; off >>= 1)
#pragma unroll
    for (int r = 0; r < 4; ++r) mrow[r] = fmaxf(mrow[r], __shfl_xor(mrow[r], off));
  if (lr == 0)
#pragma unroll
    for (int r = 0; r < 4; ++r) wred[wave][quad * 4 + r] = mrow[r];
  __syncthreads();
#pragma unroll
  for (int r = 0; r < 4; ++r) {
    int row = quad * 4 + r;
    mrow[r] = fmaxf(fmaxf(wred[0][row], wred[1][row]), fmaxf(wred[2][row], wred[3][row]));
  }
  __syncthreads();  // wred reused for sums

  // ---- exp + row sum ----
  float srow[4] = {0.f, 0.f, 0.f, 0.f};
#pragma unroll
  for (int f = 0; f < 32; ++f)
#pragma unroll
    for (int r = 0; r < 4; ++r) {
      float e = __expf(s[f][r] - mrow[r]);
      s[f][r] = e;
      srow[r] += e;
    }
#pragma unroll
  for (int off = 8; off >= 1; off >>= 1)
#pragma unroll
    for (int r = 0; r < 4; ++r) srow[r] += __shfl_xor(srow[r], off);
  if (lr == 0)
#pragma unroll
    for (int r = 0; r < 4; ++r) wred[wave][quad * 4 + r] = srow[r];
  __syncthreads();
  float inv[4];
#pragma unroll
  for (int r = 0; r < 4; ++r) {
    int row = quad * 4 + r;
    inv[r] = 1.0f / (wred[0][row] + wred[1][row] + wred[2][row] + wred[3][row]);
  }

  // ---- per 128-col chunk: stage fp32 P in wave-private LDS, coalesced probs, PV ----
  // No block barriers needed: pf[wave] is wave-private and DS ops are in-order per wave.
  float* pw = pf[wave];
  const short* Vb = vT + (size_t)h * HDIM * SEQ;
  floatx4 cacc[4] = {};
  int prow = lane >> 5;    // 0/1
  int pchunk = lane & 31;  // float4 index within 128-col row

#pragma unroll
  for (int c = 0; c < 4; ++c) {
    // A: registers -> fp32 LDS [16][128]
#pragma unroll
    for (int fi = 0; fi < 8; ++fi) {
      int f = c * 8 + fi;
#pragma unroll
      for (int r = 0; r < 4; ++r)
        pw[(quad * 4 + r) * PSTRF + fi * 16 + lr] = s[f][r] * inv[r];
    }
    // B: coalesced non-temporal probs store (512B contiguous per row segment)
#pragma unroll
    for (int i = 0; i < 8; ++i) {
      int row = i * 2 + prow;
      floatx4 v4 = *(const floatx4*)(pw + row * PSTRF + pchunk * 4);
      __builtin_nontemporal_store(
          v4, (floatx4*)(probs + ((size_t)h * SEQ + m0 + row) * SEQ + nb + c * 128 + pchunk * 4));
    }
    // C: PV — read fp32 P, convert to bf16 A-frag, MFMA against vT
#pragma unroll
    for (int kt = 0; kt < 128; kt += 32) {
      const float* pa = pw + lr * PSTRF + kt + quad * 8;
      floatx4 p0 = *(const floatx4*)(pa);
      floatx4 p1 = *(const floatx4*)(pa + 4);
      short8 a;
#pragma unroll
      for (int j = 0; j < 4; ++j) {
        a[j] = f2bf(p0[j]);
        a[4 + j] = f2bf(p1[j]);
      }
#pragma unroll
      for (int f = 0; f < 4; ++f) {
        short8 b = *(const short8*)(Vb + (size_t)(f * 16 + lr) * SEQ + nb + c * 128 + kt + quad * 8);
        cacc[f] = __builtin_amdgcn_mfma_f32_16x16x32_bf16(a, b, cacc[f], 0, 0, 0);
      }
    }
  }

  // ---- cross-wave ctx reduction ----
#pragma unroll
  for (int f = 0; f < 4; ++f)
#pragma unroll
    for (int r = 0; r < 4; ++r) partial[wave][quad * 4 + r][f * 16 + lr] = cacc[f][r];
  __syncthreads();
  for (int e = threadIdx.x; e < 16 * 64; e += 256) {
    int m = e >> 6, d = e & 63;
    float v = partial[0][m][d] + partial[1][m][d] + partial[2][m][d] + partial[3][m][d];
    ctx[(size_t)(m0 + m) * DMODEL + h * HDIM + d] = v;
  }
}

extern "C" void kernel_launch(void* const* d_in, const int* in_sizes, int n_in,
                              void* d_out, int out_size, void* d_ws, size_t ws_size,
                              hipStream_t stream) {
  const float* X = (const float*)d_in[0];
  const float* Wq = (const float*)d_in[1];
  const float* Wk = (const float*)d_in[2];
  const float* Wv = (const float*)d_in[3];

  float* ctx = (float*)d_out;
  float* probs = (float*)d_out + (size_t)SEQ * DMODEL;

  short* Xb = (short*)d_ws;                      // [2048][1024] bf16
  short* Wt = Xb + (size_t)SEQ * DMODEL;         // [3*1024][1024] bf16 (B^T)
  short* qb = Wt + (size_t)3 * DMODEL * DMODEL;  // [16][2048][64]
  short* kb = qb + (size_t)NHEADS * SEQ * HDIM;  // [16][2048][64]
  short* vT = kb + (size_t)NHEADS * SEQ * HDIM;  // [16][64][2048]

  cast_bf16_kernel<<<(SEQ * DMODEL + 255) / 256, 256, 0, stream>>>(X, Xb, SEQ * DMODEL);
  dim3 tb(32, 8), tg(32, 32);
  transpose_cast_kernel<<<tg, tb, 0, stream>>>(Wq, Wt);
  transpose_cast_kernel<<<tg, tb, 0, stream>>>(Wk, Wt + (size_t)DMODEL * DMODEL);
  transpose_cast_kernel<<<tg, tb, 0, stream>>>(Wv, Wt + (size_t)2 * DMODEL * DMODEL);

  qkv_gemm_kernel<<<dim3(3 * DMODEL / 128, SEQ / 128), 256, 0, stream>>>(Xb, Wt, qb, kb, vT);
  attn_fused_kernel<<<dim3(SEQ / 16, NHEADS), 256, 0, stream>>>(qb, kb, vT, probs, ctx);
}